// Round 2
// baseline (303.526 us; speedup 1.0000x reference)
//
#include <hip/hip_runtime.h>
#include <stdint.h>

#define BLOCK 256
#define ITEMS 8
#define TILE (BLOCK * ITEMS)
#define MAXSEG 64
#define THRESH 0.1f

typedef unsigned long long u64;

__device__ __forceinline__ int find_seg(const int* rs, int n_seg, int i) {
    // largest s with rs[s] <= i
    int lo = 0, hi = n_seg;
    while (hi - lo > 1) {
        int mid = (lo + hi) >> 1;
        if (rs[mid] <= i) lo = mid; else hi = mid;
    }
    return lo;
}

__global__ void k_init(u64* seg_packed, int n_seg) {
    int t = blockIdx.x * blockDim.x + threadIdx.x;
    if (t < n_seg) seg_packed[t] = ~0ull;   // (score_bits=+max, idx=max)
}

// Pass 1: per-segment packed (min score bits << 32 | index) via wave-reduce + 1 atomic/wave.
// Scores are in [0,1) so uint-bit order == float order; packed min gives min score, tie -> min idx.
__global__ __launch_bounds__(BLOCK) void k_min(const float* __restrict__ score,
        const int* __restrict__ row_splits, int n_seg, int n,
        u64* __restrict__ seg_packed) {
    __shared__ int rs[MAXSEG + 1];
    for (int j = threadIdx.x; j <= n_seg; j += BLOCK) rs[j] = row_splits[j];
    __syncthreads();
    int lane = threadIdx.x & 63, wv = threadIdx.x >> 6;
    int wbase = blockIdx.x * TILE + wv * 64 * ITEMS;
    if (wbase >= n) return;                       // whole wave exits together
    int wend = min(n, wbase + 64 * ITEMS) - 1;
    int sf = find_seg(rs, n_seg, wbase);
    int sl = find_seg(rs, n_seg, wend);           // at most one boundary per wave (seg len >> 512)
    int tbase = wbase + lane * ITEMS;
    u64 m0 = ~0ull, m1 = ~0ull;
    if (tbase < n) {
        float v[ITEMS];
        if (tbase + ITEMS <= n) {
            float4 f0 = *(const float4*)(score + tbase);
            float4 f1 = *(const float4*)(score + tbase + 4);
            v[0]=f0.x; v[1]=f0.y; v[2]=f0.z; v[3]=f0.w;
            v[4]=f1.x; v[5]=f1.y; v[6]=f1.z; v[7]=f1.w;
        } else {
            for (int j = 0; j < ITEMS; j++) v[j] = (tbase + j < n) ? score[tbase + j] : 1.0f;
        }
        int seg = sf;
        #pragma unroll
        for (int j = 0; j < ITEMS; j++) {
            int i = tbase + j;
            if (i >= n) break;
            while (seg < sl && rs[seg + 1] <= i) seg++;
            u64 p = ((u64)__float_as_uint(v[j]) << 32) | (unsigned int)i;
            if (seg == sf) m0 = min(m0, p); else m1 = min(m1, p);
        }
    }
    for (int o = 32; o > 0; o >>= 1) {
        m0 = min(m0, (u64)__shfl_down((unsigned long long)m0, o, 64));
        if (sl != sf) m1 = min(m1, (u64)__shfl_down((unsigned long long)m1, o, 64));
    }
    if (lane == 0) {
        if (m0 != ~0ull) atomicMin(&seg_packed[sf], m0);
        if (sl != sf && m1 != ~0ull) atomicMin(&seg_packed[sl], m1);
    }
}

// Pass 2: per-block keep count (no atomics)
__global__ __launch_bounds__(BLOCK) void k_count(const float* __restrict__ score,
        const int* __restrict__ row_splits, int n_seg, int n,
        const u64* __restrict__ seg_packed,
        int* __restrict__ block_counts) {
    __shared__ int rs[MAXSEG + 1];
    __shared__ unsigned int smin[MAXSEG];
    __shared__ int wsum[BLOCK / 64];
    for (int j = threadIdx.x; j <= n_seg; j += BLOCK) rs[j] = row_splits[j];
    for (int j = threadIdx.x; j < n_seg; j += BLOCK) smin[j] = (unsigned int)(seg_packed[j] >> 32);
    __syncthreads();
    int tbase = blockIdx.x * TILE + threadIdx.x * ITEMS;
    int c = 0;
    if (tbase < n) {
        float v[ITEMS];
        if (tbase + ITEMS <= n) {
            float4 f0 = *(const float4*)(score + tbase);
            float4 f1 = *(const float4*)(score + tbase + 4);
            v[0]=f0.x; v[1]=f0.y; v[2]=f0.z; v[3]=f0.w;
            v[4]=f1.x; v[5]=f1.y; v[6]=f1.z; v[7]=f1.w;
        } else {
            for (int j = 0; j < ITEMS; j++) v[j] = (tbase + j < n) ? score[tbase + j] : 1.0f;
        }
        int seg = find_seg(rs, n_seg, tbase);
        #pragma unroll
        for (int j = 0; j < ITEMS; j++) {
            int i = tbase + j;
            if (i >= n) break;
            while (seg < n_seg - 1 && rs[seg + 1] <= i) seg++;
            bool keep = (v[j] > THRESH) || (__float_as_uint(v[j]) == smin[seg]);
            c += keep ? 1 : 0;
        }
    }
    int lane = threadIdx.x & 63, w = threadIdx.x >> 6;
    int s = c;
    for (int o = 32; o > 0; o >>= 1) s += __shfl_down(s, o, 64);
    if (lane == 0) wsum[w] = s;
    __syncthreads();
    if (threadIdx.x == 0)
        block_counts[blockIdx.x] = wsum[0] + wsum[1] + wsum[2] + wsum[3];
}

// Pass 3: single-block exclusive scan of nb block counts (serial chunk + shfl scan)
__global__ __launch_bounds__(BLOCK) void k_scan(const int* __restrict__ counts,
                                                int* __restrict__ offsets, int nb) {
    __shared__ int wtot[BLOCK / 64];
    int per = (nb + BLOCK - 1) / BLOCK;
    int s = per * threadIdx.x, e = min(nb, s + per);
    int sum = 0;
    for (int i = s; i < e; i++) sum += counts[i];
    int lane = threadIdx.x & 63, wv = threadIdx.x >> 6;
    int incl = sum;
    for (int o = 1; o < 64; o <<= 1) {
        int t = __shfl_up(incl, o, 64);
        if (lane >= o) incl += t;
    }
    if (lane == 63) wtot[wv] = incl;
    __syncthreads();
    int excl = incl - sum;
    for (int k = 0; k < wv; k++) excl += wtot[k];
    for (int i = s; i < e; i++) { offsets[i] = excl; excl += counts[i]; }
}

// Pass 4: exclusive kept-count at query indices -> newrs + rep_pos (one wave per query)
__global__ __launch_bounds__(BLOCK) void k_query(const float* __restrict__ score,
        const int* __restrict__ row_splits, int n_seg, int n, int M,
        const u64* __restrict__ seg_packed,
        const int* __restrict__ block_offsets,
        int* __restrict__ rep_pos, int* __restrict__ newrs_out) {
    __shared__ int rs[MAXSEG + 1];
    __shared__ unsigned int smin[MAXSEG];
    __shared__ int fmin[MAXSEG];
    for (int j = threadIdx.x; j <= n_seg; j += BLOCK) rs[j] = row_splits[j];
    for (int j = threadIdx.x; j < n_seg; j += BLOCK) {
        u64 p = seg_packed[j];
        smin[j] = (unsigned int)(p >> 32);
        fmin[j] = (int)(p & 0xFFFFFFFFu);
    }
    __syncthreads();
    int wv = threadIdx.x >> 6, lane = threadIdx.x & 63;
    int q = blockIdx.x * (BLOCK / 64) + wv;
    int nq = 2 * n_seg + 1;
    if (q >= nq) return;
    int idx = (q <= n_seg) ? rs[q] : fmin[q - (n_seg + 1)];
    int result;
    if (idx >= n) {
        result = M;
    } else {
        int b = idx / TILE;
        int cnt = 0;
        for (int i = b * TILE + lane; i < idx; i += 64) {
            float v = score[i];
            int seg = find_seg(rs, n_seg, i);
            if ((v > THRESH) || (__float_as_uint(v) == smin[seg])) cnt++;
        }
        for (int o = 32; o > 0; o >>= 1) cnt += __shfl_down(cnt, o, 64);
        result = block_offsets[b] + cnt;
    }
    if (lane == 0) {
        if (q <= n_seg) newrs_out[q] = result;
        else rep_pos[q - (n_seg + 1)] = result;
    }
}

// Pass 5: outputs. Stage bg + compacted sel in LDS, then phase-aligned int4 stores.
__global__ __launch_bounds__(BLOCK) void k_output(const float* __restrict__ score,
        const int* __restrict__ row_splits, int n_seg, int n,
        const u64* __restrict__ seg_packed,
        const int* __restrict__ rep_pos,
        const int* __restrict__ block_offsets,
        int* __restrict__ sel_out, int* __restrict__ back_out) {
    __shared__ int rs[MAXSEG + 1];
    __shared__ unsigned int smin[MAXSEG];
    __shared__ int srep[MAXSEG];
    __shared__ int wsum[BLOCK / 64];
    __shared__ int sbg[TILE];
    __shared__ int skel[TILE];
    for (int j = threadIdx.x; j <= n_seg; j += BLOCK) rs[j] = row_splits[j];
    for (int j = threadIdx.x; j < n_seg; j += BLOCK) {
        smin[j] = (unsigned int)(seg_packed[j] >> 32);
        srep[j] = rep_pos[j];
    }
    __syncthreads();
    int base = blockIdx.x * TILE;
    int lim = min(TILE, n - base);
    int tbase = base + threadIdx.x * ITEMS;
    float v[ITEMS];
    bool kf[ITEMS];
    int c = 0, seg0 = 0;
    if (tbase < n) {
        if (tbase + ITEMS <= n) {
            float4 f0 = *(const float4*)(score + tbase);
            float4 f1 = *(const float4*)(score + tbase + 4);
            v[0]=f0.x; v[1]=f0.y; v[2]=f0.z; v[3]=f0.w;
            v[4]=f1.x; v[5]=f1.y; v[6]=f1.z; v[7]=f1.w;
        } else {
            for (int j = 0; j < ITEMS; j++) v[j] = (tbase + j < n) ? score[tbase + j] : 1.0f;
        }
        int seg = find_seg(rs, n_seg, tbase);
        seg0 = seg;
        #pragma unroll
        for (int j = 0; j < ITEMS; j++) {
            int i = tbase + j;
            if (i >= n) { kf[j] = false; continue; }
            while (seg < n_seg - 1 && rs[seg + 1] <= i) seg++;
            kf[j] = (v[j] > THRESH) || (__float_as_uint(v[j]) == smin[seg]);
            c += kf[j] ? 1 : 0;
        }
    } else {
        for (int j = 0; j < ITEMS; j++) kf[j] = false;
    }
    // block exclusive scan of per-thread counts
    int lane = threadIdx.x & 63, w = threadIdx.x >> 6;
    int incl = c;
    for (int o = 1; o < 64; o <<= 1) {
        int t = __shfl_up(incl, o, 64);
        if (lane >= o) incl += t;
    }
    if (lane == 63) wsum[w] = incl;
    __syncthreads();
    int excl = incl - c;
    for (int k = 0; k < w; k++) excl += wsum[k];
    int bo = block_offsets[blockIdx.x];

    // stage into LDS
    if (tbase < n) {
        int kp = excl;
        int seg = seg0;
        #pragma unroll
        for (int j = 0; j < ITEMS; j++) {
            int i = tbase + j;
            if (i >= n) break;
            while (seg < n_seg - 1 && rs[seg + 1] <= i) seg++;
            if (kf[j]) {
                sbg[i - base] = bo + kp;
                skel[kp] = i;
                kp++;
            } else {
                sbg[i - base] = srep[seg];
            }
        }
    }
    __syncthreads();

    // back_out[base .. base+lim): phase-aligned int4 stores
    {
        uintptr_t addr = (uintptr_t)(back_out + base);
        int st = (int)((4 - ((addr >> 2) & 3)) & 3);
        if (st > lim) st = lim;
        int nv = (lim - st) >> 2;
        for (int t = threadIdx.x; t < nv; t += BLOCK) {
            int j = st + 4 * t;
            *(int4*)(back_out + base + j) = make_int4(sbg[j], sbg[j+1], sbg[j+2], sbg[j+3]);
        }
        for (int j = threadIdx.x; j < st; j += BLOCK) back_out[base + j] = sbg[j];
        for (int j = st + 4 * nv + threadIdx.x; j < lim; j += BLOCK) back_out[base + j] = sbg[j];
    }
    // sel_out[bo .. bo+tot): phase-aligned int4 stores
    {
        int tot = wsum[0] + wsum[1] + wsum[2] + wsum[3];
        uintptr_t addr = (uintptr_t)(sel_out + bo);
        int st = (int)((4 - ((addr >> 2) & 3)) & 3);
        if (st > tot) st = tot;
        int nv = (tot - st) >> 2;
        for (int t = threadIdx.x; t < nv; t += BLOCK) {
            int j = st + 4 * t;
            *(int4*)(sel_out + bo + j) = make_int4(skel[j], skel[j+1], skel[j+2], skel[j+3]);
        }
        for (int j = threadIdx.x; j < st; j += BLOCK) sel_out[bo + j] = skel[j];
        for (int j = st + 4 * nv + threadIdx.x; j < tot; j += BLOCK) sel_out[bo + j] = skel[j];
    }
}

extern "C" void kernel_launch(void* const* d_in, const int* in_sizes, int n_in,
                              void* d_out, int out_size, void* d_ws, size_t ws_size,
                              hipStream_t stream) {
    const float* score = (const float*)d_in[0];
    const int* row_splits = (const int*)d_in[1];
    int n = in_sizes[0];
    int n_seg = in_sizes[1] - 1;
    int M = out_size - (n_seg + 1) - n;
    int nb = (n + TILE - 1) / TILE;

    u64* seg_packed    = (u64*)d_ws;               // 64 * 8B
    int* rep_pos       = (int*)d_ws + 128;
    int* block_counts  = (int*)d_ws + 192;
    int* block_offsets = block_counts + nb;

    int* out = (int*)d_out;
    int* sel_out   = out;
    int* newrs_out = out + M;
    int* back_out  = out + M + (n_seg + 1);

    hipLaunchKernelGGL(k_init, dim3(1), dim3(64), 0, stream, seg_packed, n_seg);
    hipLaunchKernelGGL(k_min, dim3(nb), dim3(BLOCK), 0, stream,
                       score, row_splits, n_seg, n, seg_packed);
    hipLaunchKernelGGL(k_count, dim3(nb), dim3(BLOCK), 0, stream,
                       score, row_splits, n_seg, n, seg_packed, block_counts);
    hipLaunchKernelGGL(k_scan, dim3(1), dim3(BLOCK), 0, stream,
                       block_counts, block_offsets, nb);
    int nq = 2 * n_seg + 1;
    int qblocks = (nq + (BLOCK / 64) - 1) / (BLOCK / 64);
    hipLaunchKernelGGL(k_query, dim3(qblocks), dim3(BLOCK), 0, stream,
                       score, row_splits, n_seg, n, M, seg_packed,
                       block_offsets, rep_pos, newrs_out);
    hipLaunchKernelGGL(k_output, dim3(nb), dim3(BLOCK), 0, stream,
                       score, row_splits, n_seg, n, seg_packed, rep_pos,
                       block_offsets, sel_out, back_out);
}

// Round 3
// 197.169 us; speedup vs baseline: 1.5394x; 1.5394x over previous
//
#include <hip/hip_runtime.h>
#include <stdint.h>

#define BLOCK 256
#define ITEMS 8
#define TILE (BLOCK * ITEMS)   // 2048 elements per block
#define WPB (TILE / 64)        // 32 bitmask words per block
#define MAXSEG 64
#define THRESH 0.1f

typedef unsigned long long u64;

__device__ __forceinline__ int find_seg(const int* rs, int n_seg, int i) {
    // largest s with rs[s] <= i
    int lo = 0, hi = n_seg;
    while (hi - lo > 1) {
        int mid = (lo + hi) >> 1;
        if (rs[mid] <= i) lo = mid; else hi = mid;
    }
    return lo;
}

// Pass 1: per-block packed (min score bits << 32 | index). NO atomics: each block
// writes its <=2 (seg,val) partials to dedicated slots. Assumes a 512-elem wave
// spans <=1 segment boundary (seg len >> 512 here).
__global__ __launch_bounds__(BLOCK) void k_min(const float* __restrict__ score,
        const int* __restrict__ row_splits, int n_seg, int n,
        u64* __restrict__ partial_val, int* __restrict__ partial_seg) {
    __shared__ int rs[MAXSEG + 1];
    __shared__ u64 wval[8];
    __shared__ int wseg[8];
    for (int j = threadIdx.x; j <= n_seg; j += BLOCK) rs[j] = row_splits[j];
    __syncthreads();
    int lane = threadIdx.x & 63, wv = threadIdx.x >> 6;
    int wbase = blockIdx.x * TILE + wv * (64 * ITEMS);
    u64 m0 = ~0ull, m1 = ~0ull;
    int sf = 0, sl = 0;
    if (wbase < n) {
        int wend = min(n, wbase + 64 * ITEMS) - 1;
        sf = find_seg(rs, n_seg, wbase);
        sl = find_seg(rs, n_seg, wend);
        int tbase = wbase + lane * ITEMS;
        if (tbase < n) {
            float v[ITEMS];
            if (tbase + ITEMS <= n) {
                float4 f0 = *(const float4*)(score + tbase);
                float4 f1 = *(const float4*)(score + tbase + 4);
                v[0]=f0.x; v[1]=f0.y; v[2]=f0.z; v[3]=f0.w;
                v[4]=f1.x; v[5]=f1.y; v[6]=f1.z; v[7]=f1.w;
            } else {
                for (int j = 0; j < ITEMS; j++) v[j] = (tbase + j < n) ? score[tbase + j] : 1.0f;
            }
            int seg = sf;
            #pragma unroll
            for (int j = 0; j < ITEMS; j++) {
                int i = tbase + j;
                if (i >= n) break;
                while (seg < sl && rs[seg + 1] <= i) seg++;
                u64 p = ((u64)__float_as_uint(v[j]) << 32) | (unsigned int)i;
                if (seg == sf) m0 = min(m0, p); else m1 = min(m1, p);
            }
        }
        for (int o = 32; o > 0; o >>= 1) {
            m0 = min(m0, (u64)__shfl_down((unsigned long long)m0, o, 64));
            m1 = min(m1, (u64)__shfl_down((unsigned long long)m1, o, 64));
        }
    }
    if (lane == 0) {
        wval[2 * wv] = m0;     wseg[2 * wv] = sf;
        wval[2 * wv + 1] = m1; wseg[2 * wv + 1] = (sl != sf) ? sl : -1;
    }
    __syncthreads();
    if (threadIdx.x == 0) {
        int base = blockIdx.x * TILE;
        int endi = min(n, base + TILE) - 1;
        int s0 = find_seg(rs, n_seg, base);
        int s1 = find_seg(rs, n_seg, endi);
        u64 o0 = ~0ull, o1 = ~0ull;
        for (int k = 0; k < 8; k++) {
            if (wseg[k] == s0) o0 = min(o0, wval[k]);
            else if (wseg[k] == s1) o1 = min(o1, wval[k]);
        }
        partial_val[2 * blockIdx.x] = o0;
        partial_seg[2 * blockIdx.x] = s0;
        partial_val[2 * blockIdx.x + 1] = o1;
        partial_seg[2 * blockIdx.x + 1] = (s1 != s0) ? s1 : -1;
    }
}

// Pass 2: one wave per segment reduces its block partials -> seg_packed[s].
// Writes every slot, so no init kernel needed.
__global__ __launch_bounds__(BLOCK) void k_reduce(const int* __restrict__ row_splits,
        int n_seg, int n,
        const u64* __restrict__ partial_val, const int* __restrict__ partial_seg,
        u64* __restrict__ seg_packed) {
    int lane = threadIdx.x & 63, wv = threadIdx.x >> 6;
    int s = blockIdx.x * (BLOCK / 64) + wv;
    if (s >= n_seg) return;
    int lo = row_splits[s], hi = row_splits[s + 1];
    u64 m = ~0ull;
    if (hi > lo) {
        int b0 = lo / TILE, b1 = (hi - 1) / TILE;
        for (int e = 2 * b0 + lane; e <= 2 * b1 + 1; e += 64) {
            if (partial_seg[e] == s) m = min(m, partial_val[e]);
        }
    }
    for (int o = 32; o > 0; o >>= 1)
        m = min(m, (u64)__shfl_down((unsigned long long)m, o, 64));
    if (lane == 0) seg_packed[s] = m;
}

// Pass 3: keep bitmask (ballot-built) + per-block counts. No atomics.
__global__ __launch_bounds__(BLOCK) void k_count(const float* __restrict__ score,
        const int* __restrict__ row_splits, int n_seg, int n,
        const u64* __restrict__ seg_packed,
        u64* __restrict__ bitmask, int* __restrict__ block_counts) {
    __shared__ int rs[MAXSEG + 1];
    __shared__ unsigned int smin[MAXSEG];
    __shared__ int wsum[BLOCK / 64];
    for (int j = threadIdx.x; j <= n_seg; j += BLOCK) rs[j] = row_splits[j];
    for (int j = threadIdx.x; j < n_seg; j += BLOCK) smin[j] = (unsigned int)(seg_packed[j] >> 32);
    __syncthreads();
    int lane = threadIdx.x & 63, wv = threadIdx.x >> 6;
    int wbase = blockIdx.x * TILE + wv * 512;
    int nwords = (n + 63) >> 6;
    u64 myword = 0;
    int cnt = 0;
    #pragma unroll
    for (int it = 0; it < 8; it++) {
        int i = wbase + it * 64 + lane;
        bool keep = false;
        if (i < n) {
            float v = score[i];
            int seg = find_seg(rs, n_seg, i);
            keep = (v > THRESH) || (__float_as_uint(v) == smin[seg]);
        }
        u64 bal = __ballot(keep);
        if (lane == it) myword = bal;
        cnt += __popcll(bal);
    }
    if (lane < 8) {
        int w = (wbase >> 6) + lane;
        if (w < nwords) bitmask[w] = myword;
    }
    if (lane == 0) wsum[wv] = cnt;
    __syncthreads();
    if (threadIdx.x == 0)
        block_counts[blockIdx.x] = wsum[0] + wsum[1] + wsum[2] + wsum[3];
}

// Pass 4: single-block exclusive scan of nb block counts
__global__ __launch_bounds__(BLOCK) void k_scan(const int* __restrict__ counts,
                                                int* __restrict__ offsets, int nb) {
    __shared__ int wtot[BLOCK / 64];
    int per = (nb + BLOCK - 1) / BLOCK;
    int s = per * threadIdx.x, e = min(nb, s + per);
    int sum = 0;
    for (int i = s; i < e; i++) sum += counts[i];
    int lane = threadIdx.x & 63, wv = threadIdx.x >> 6;
    int incl = sum;
    for (int o = 1; o < 64; o <<= 1) {
        int t = __shfl_up(incl, o, 64);
        if (lane >= o) incl += t;
    }
    if (lane == 63) wtot[wv] = incl;
    __syncthreads();
    int excl = incl - sum;
    for (int k = 0; k < wv; k++) excl += wtot[k];
    for (int i = s; i < e; i++) { offsets[i] = excl; excl += counts[i]; }
}

// Pass 5: exclusive kept-count at query indices via bitmask popcount -> newrs + rep_pos
__global__ __launch_bounds__(BLOCK) void k_query(const int* __restrict__ row_splits,
        int n_seg, int n, int M,
        const u64* __restrict__ seg_packed, const u64* __restrict__ bitmask,
        const int* __restrict__ block_offsets,
        int* __restrict__ rep_pos, int* __restrict__ newrs_out) {
    int lane = threadIdx.x & 63, wv = threadIdx.x >> 6;
    int q = blockIdx.x * (BLOCK / 64) + wv;
    int nq = 2 * n_seg + 1;
    if (q >= nq) return;
    unsigned int uidx;
    if (q <= n_seg) uidx = (unsigned int)row_splits[q];
    else uidx = (unsigned int)(seg_packed[q - (n_seg + 1)] & 0xFFFFFFFFu);
    int result;
    if (uidx >= (unsigned int)n) {
        result = M;
    } else {
        int idx = (int)uidx;
        int b = idx / TILE;
        int w0 = b * WPB;
        int wq = idx >> 6;
        int cnt = 0;
        for (int w = w0 + lane; w < wq; w += 64) cnt += __popcll(bitmask[w]);
        if (lane == 0 && (idx & 63)) cnt += __popcll(bitmask[wq] & ((1ull << (idx & 63)) - 1));
        for (int o = 32; o > 0; o >>= 1) cnt += __shfl_down(cnt, o, 64);
        result = block_offsets[b] + cnt;
    }
    if (lane == 0) {
        if (q <= n_seg) newrs_out[q] = result;
        else rep_pos[q - (n_seg + 1)] = result;
    }
}

// Pass 6: outputs from bitmask only (no score re-read).
__global__ __launch_bounds__(BLOCK) void k_output(const int* __restrict__ row_splits,
        int n_seg, int n,
        const int* __restrict__ rep_pos, const u64* __restrict__ bitmask,
        const int* __restrict__ block_offsets,
        int* __restrict__ sel_out, int* __restrict__ back_out) {
    __shared__ int rs[MAXSEG + 1];
    __shared__ int srep[MAXSEG];
    __shared__ u64 swords[WPB];
    __shared__ int wpre[WPB];
    for (int j = threadIdx.x; j <= n_seg; j += BLOCK) rs[j] = row_splits[j];
    for (int j = threadIdx.x; j < n_seg; j += BLOCK) srep[j] = rep_pos[j];
    int base = blockIdx.x * TILE;
    int nw = min(WPB, (n - base + 63) >> 6);
    for (int j = threadIdx.x; j < nw; j += BLOCK) swords[j] = bitmask[(base >> 6) + j];
    __syncthreads();
    if (threadIdx.x == 0) {
        int acc = 0;
        for (int k = 0; k < nw; k++) { wpre[k] = acc; acc += __popcll(swords[k]); }
    }
    __syncthreads();
    int bo = block_offsets[blockIdx.x];
    int lane = threadIdx.x & 63, wv = threadIdx.x >> 6;
    #pragma unroll
    for (int it = 0; it < 8; it++) {
        int widx = wv * 8 + it;
        int i = base + widx * 64 + lane;
        if (i < n) {
            u64 word = swords[widx];
            bool keep = (word >> lane) & 1;
            int val;
            if (keep) {
                int pos = bo + wpre[widx] + __popcll(word & ((1ull << lane) - 1));
                val = pos;
                sel_out[pos] = i;
            } else {
                int seg = find_seg(rs, n_seg, i);
                val = srep[seg];
            }
            back_out[i] = val;
        }
    }
}

extern "C" void kernel_launch(void* const* d_in, const int* in_sizes, int n_in,
                              void* d_out, int out_size, void* d_ws, size_t ws_size,
                              hipStream_t stream) {
    const float* score = (const float*)d_in[0];
    const int* row_splits = (const int*)d_in[1];
    int n = in_sizes[0];
    int n_seg = in_sizes[1] - 1;
    int M = out_size - (n_seg + 1) - n;
    int nb = (n + TILE - 1) / TILE;
    int nwords = (n + 63) / 64;
    (void)nwords;

    u64* seg_packed   = (u64*)d_ws;                      // 64 u64
    u64* partial_val  = seg_packed + 64;                 // 2*nb u64
    int* partial_seg  = (int*)(partial_val + 2 * nb);    // 2*nb int
    int* rep_pos      = partial_seg + 2 * nb;            // 64 int
    int* block_counts = rep_pos + 64;                    // nb int
    int* block_offsets= block_counts + nb;               // nb int
    uintptr_t bm_addr = (uintptr_t)(block_offsets + nb);
    bm_addr = (bm_addr + 7) & ~(uintptr_t)7;
    u64* bitmask      = (u64*)bm_addr;                   // nwords u64

    int* out = (int*)d_out;
    int* sel_out   = out;
    int* newrs_out = out + M;
    int* back_out  = out + M + (n_seg + 1);

    hipLaunchKernelGGL(k_min, dim3(nb), dim3(BLOCK), 0, stream,
                       score, row_splits, n_seg, n, partial_val, partial_seg);
    int rblocks = (n_seg + (BLOCK / 64) - 1) / (BLOCK / 64);
    hipLaunchKernelGGL(k_reduce, dim3(rblocks), dim3(BLOCK), 0, stream,
                       row_splits, n_seg, n, partial_val, partial_seg, seg_packed);
    hipLaunchKernelGGL(k_count, dim3(nb), dim3(BLOCK), 0, stream,
                       score, row_splits, n_seg, n, seg_packed, bitmask, block_counts);
    hipLaunchKernelGGL(k_scan, dim3(1), dim3(BLOCK), 0, stream,
                       block_counts, block_offsets, nb);
    int nq = 2 * n_seg + 1;
    int qblocks = (nq + (BLOCK / 64) - 1) / (BLOCK / 64);
    hipLaunchKernelGGL(k_query, dim3(qblocks), dim3(BLOCK), 0, stream,
                       row_splits, n_seg, n, M, seg_packed, bitmask,
                       block_offsets, rep_pos, newrs_out);
    hipLaunchKernelGGL(k_output, dim3(nb), dim3(BLOCK), 0, stream,
                       row_splits, n_seg, n, rep_pos, bitmask,
                       block_offsets, sel_out, back_out);
}